// Round 11
// baseline (17085.512 us; speedup 1.0000x reference)
//
#include <hip/hip_runtime.h>
#include <stdint.h>

// HardLSTM R11 = R3 (proven 9.27ms anchor) byte-for-byte, plus two isolated,
// previously-derisked deltas:
//  1) LDK 328->324 (648B LDS row stride; R4/R6/R8 measured ~0 bank conflicts
//     vs R3's 30M conflict-cycles).
//  2) h-load/x-MFMA overlap: issue the 10 h dwordx4 loads un-waited, run the
//     30 x-half MFMAs from LDS, then vmcnt(0)+sched_barrier(0) (rule #18)
//     before the 20 h-half MFMAs. This exact reorder ran correctly in R6/R7.
// Protocol, barriers, staging, publish identical to R3: 2 groups x 10 wgs x
// 512 thr; full K=640 weights in regs (bf16 hi/lo); h state bf16-hi only,
// double-buffered; wave0 16-lane poll (AGENT atomic); coalesced wave0
// publish (sc0 sc1) + vmcnt drain + SYSTEM flag store.

#define T_STEPS 2000
#define BATCH   32
#define IDIM    320
#define HDIM    320
#define NWG     20
#define WPG     10
#define NTH     512
#define GB      16
#define UPW     32
#define LDK     324            // 648B row stride: measured ~0 bank conflicts
#define SSZ     (BATCH*HDIM)   // 10240 ushorts per h slot

typedef __attribute__((ext_vector_type(8))) short short8;
typedef __attribute__((ext_vector_type(4))) float f32x4;
typedef __attribute__((ext_vector_type(4))) unsigned short ushort4v;
typedef __attribute__((ext_vector_type(4))) unsigned int uint32x4;

static __device__ __forceinline__ unsigned short f2bf(float f) {
    uint32_t u = __float_as_uint(f);
    u += 0x7FFFu + ((u >> 16) & 1u);   // RTNE
    return (unsigned short)(u >> 16);
}
static __device__ __forceinline__ float bf2f(unsigned short s) {
    return __uint_as_float(((uint32_t)s) << 16);
}
static __device__ __forceinline__ float sat01(float v)  { return fminf(fmaxf(v, 0.f), 1.f); }
static __device__ __forceinline__ float clamp1(float v) { return fminf(fmaxf(v, -1.f), 1.f); }

static __device__ __forceinline__ void cvt_store(unsigned short* hi_p,
                                                 unsigned short* lo_p, float4 v) {
    ushort4v hi, lo;
    hi[0] = f2bf(v.x); lo[0] = f2bf(v.x - bf2f(hi[0]));
    hi[1] = f2bf(v.y); lo[1] = f2bf(v.y - bf2f(hi[1]));
    hi[2] = f2bf(v.z); lo[2] = f2bf(v.z - bf2f(hi[2]));
    hi[3] = f2bf(v.w); lo[3] = f2bf(v.w - bf2f(hi[3]));
    *(ushort4v*)hi_p = hi;
    *(ushort4v*)lo_p = lo;
}

__global__ __launch_bounds__(NTH, 2)
void hard_lstm(const float* __restrict__ x, const float* __restrict__ w_ih,
               const float* __restrict__ w_hh, const float* __restrict__ b_ih,
               const float* __restrict__ b_hh, float* __restrict__ out,
               unsigned short* __restrict__ hb, uint32_t* __restrict__ flags)
{
    __shared__ __align__(16) unsigned short xb[2][2][GB][LDK];  // [slot][hi/lo][b][k]
    __shared__ __align__(16) unsigned short h1s[2][GB][UPW];    // bf16 h1 scratch

    const int tid  = threadIdx.x;
    const int wgg  = blockIdx.x;
    const int grp  = wgg / WPG;
    const int wgl  = wgg % WPG;
    const int wave = tid >> 6;
    const int lane = tid & 63;
    const int col  = lane & 15;    // MFMA A-row / B-col (batch within group)
    const int q    = lane >> 4;    // k-chunk / output row-quad

    // ---- A fragments (weights) -> registers, bf16 hi/lo, full K=640 ----
    short8 ahi[20], alo[20];
    {
        const int jA   = wgl * UPW + wave * 4 + (col >> 2);
        const int grow = (col & 3) * HDIM + jA;
        const float* wi = w_ih + (size_t)grow * IDIM;
        const float* wh = w_hh + (size_t)grow * HDIM;
        #pragma unroll
        for (int s = 0; s < 20; ++s) {
            #pragma unroll
            for (int jj = 0; jj < 8; ++jj) {
                int k = s * 32 + q * 8 + jj;
                float w = (k < IDIM) ? wi[k] : wh[k - IDIM];
                unsigned short hi = f2bf(w);
                ahi[s][jj] = (short)hi;
                alo[s][jj] = (short)f2bf(w - bf2f(hi));
            }
        }
    }

    const int jOut = wgl * UPW + wave * 4 + q;   // hidden unit owned by this lane
    const int bOut = grp * GB + col;             // global batch owned by this lane
    float bias4[4];
    #pragma unroll
    for (int v = 0; v < 4; ++v)
        bias4[v] = b_ih[v * HDIM + jOut] + b_hh[v * HDIM + jOut];

    // staging chunks: 1280 float4 over [16][320]; thread owns c0,c1(,c2)
    const int c0 = tid, c1 = tid + NTH, c2 = tid + 2 * NTH;
    const int b0 = c0 / 80, k0 = (c0 % 80) * 4;
    const int b1 = c1 / 80, k1 = (c1 % 80) * 4;
    const int b2 = c2 / 80, k2 = (c2 % 80) * 4;
    const bool has2 = (tid < 256);

    uint32_t* fline = flags + grp * 16;          // group's flag cacheline
    uint32_t* fpoll = &fline[lane % WPG];

    // h-fragment base (batch col, k-offset q*8), per slot
    const unsigned short* hp0 = hb + (size_t)bOut * HDIM + q * 8;

    // ---------- pre-loop: publish h(0)=0, stage x(0), flag=1 ----------
    h1s[1][col][wave * 4 + q] = 0;
    {
        const float4* xs = (const float4*)(x + (size_t)(grp * GB) * IDIM);
        float4 v0 = xs[c0], v1 = xs[c1], v2 = {};
        if (has2) v2 = xs[c2];
        cvt_store(&xb[0][0][b0][k0], &xb[0][1][b0][k0], v0);
        cvt_store(&xb[0][0][b1][k1], &xb[0][1][b1][k1], v1);
        if (has2) cvt_store(&xb[0][0][b2][k2], &xb[0][1][b2][k2], v2);
    }
    __syncthreads();
    if (wave == 0) {
        const int b = lane >> 2, part = lane & 3;
        uint32x4 d = *(const uint32x4*)&h1s[1][b][part * 8];
        unsigned short* dst = hb + (size_t)(grp * GB + b) * HDIM + wgl * UPW + part * 8;
        asm volatile("global_store_dwordx4 %0, %1, off sc0 sc1\n\t"
                     "s_waitcnt vmcnt(0)" :: "v"(dst), "v"(d) : "memory");
        if (lane == 0)
            __hip_atomic_store(&fline[wgl], 1u, __ATOMIC_RELAXED, __HIP_MEMORY_SCOPE_SYSTEM);
    }

    float c_state = 0.f;

    #pragma unroll 1
    for (int t = 0; t < T_STEPS; ++t) {
        const int slot  = t & 1;
        const int slotn = slot ^ 1;

        // ---- x(t+1) prefetch into regs (issued early; latency hides under
        //      the poll/barrier window, exactly as R3) ----
        float4 xr0 = {}, xr1 = {}, xr2 = {};
        const bool havex = (t + 1 < T_STEPS);
        if (havex) {
            const float4* xs = (const float4*)(x + ((size_t)(t + 1) * BATCH + grp * GB) * IDIM);
            xr0 = xs[c0]; xr1 = xs[c1];
            if (has2) xr2 = xs[c2];
        }

        // ---- poll: all 10 producer flags of this group >= t+1 (wave0) ----
        if (wave == 0) {
            const uint32_t tgt = (uint32_t)(t + 1);
            while (true) {
                uint32_t v = __hip_atomic_load(fpoll, __ATOMIC_RELAXED,
                                               __HIP_MEMORY_SCOPE_AGENT);
                if (__all((int)(v >= tgt))) break;
            }
        }
        __syncthreads();   // (B) step released

        // ---- issue h(t) B-fragment loads (NO wait yet — delta #2) ----
        uint32x4 hv[10];
        {
            const unsigned short* hp = hp0 + (size_t)slot * SSZ;
            asm volatile(
                "global_load_dwordx4 %0, %10, off sc0 sc1\n\t"
                "global_load_dwordx4 %1, %10, off offset:64 sc0 sc1\n\t"
                "global_load_dwordx4 %2, %10, off offset:128 sc0 sc1\n\t"
                "global_load_dwordx4 %3, %10, off offset:192 sc0 sc1\n\t"
                "global_load_dwordx4 %4, %10, off offset:256 sc0 sc1\n\t"
                "global_load_dwordx4 %5, %10, off offset:320 sc0 sc1\n\t"
                "global_load_dwordx4 %6, %10, off offset:384 sc0 sc1\n\t"
                "global_load_dwordx4 %7, %10, off offset:448 sc0 sc1\n\t"
                "global_load_dwordx4 %8, %10, off offset:512 sc0 sc1\n\t"
                "global_load_dwordx4 %9, %10, off offset:576 sc0 sc1"
                : "=&v"(hv[0]), "=&v"(hv[1]), "=&v"(hv[2]), "=&v"(hv[3]), "=&v"(hv[4]),
                  "=&v"(hv[5]), "=&v"(hv[6]), "=&v"(hv[7]), "=&v"(hv[8]), "=&v"(hv[9])
                : "v"(hp) : "memory");
        }

        // ---- x-half MFMA (30) while h loads are in flight ----
        f32x4 acc0 = {0.f, 0.f, 0.f, 0.f};
        f32x4 acc1 = {0.f, 0.f, 0.f, 0.f};
        f32x4 acc2 = {0.f, 0.f, 0.f, 0.f};
        {
            const unsigned short* bxh = &xb[slot][0][col][q * 8];
            const unsigned short* bxl = &xb[slot][1][col][q * 8];
            #pragma unroll
            for (int s = 0; s < 10; ++s) {
                short8 bh = *(const short8*)(bxh + s * 32);
                short8 bl = *(const short8*)(bxl + s * 32);
                acc0 = __builtin_amdgcn_mfma_f32_16x16x32_bf16(ahi[s], bh, acc0, 0, 0, 0);
                acc1 = __builtin_amdgcn_mfma_f32_16x16x32_bf16(alo[s], bh, acc1, 0, 0, 0);
                acc2 = __builtin_amdgcn_mfma_f32_16x16x32_bf16(ahi[s], bl, acc2, 0, 0, 0);
            }
        }

        // ---- wait h data, fence scheduler (rule #18), h-half MFMA (20) ----
        asm volatile("s_waitcnt vmcnt(0)" ::: "memory");
        __builtin_amdgcn_sched_barrier(0);
        #pragma unroll
        for (int s = 0; s < 10; ++s) {
            short8 bh = *(const short8*)&hv[s];
            acc0 = __builtin_amdgcn_mfma_f32_16x16x32_bf16(ahi[10 + s], bh, acc0, 0, 0, 0);
            acc1 = __builtin_amdgcn_mfma_f32_16x16x32_bf16(alo[10 + s], bh, acc1, 0, 0, 0);
        }

        // ---- gate math: lane owns (bOut, jOut), all 4 gates ----
        float p[4];
        #pragma unroll
        for (int v = 0; v < 4; ++v) p[v] = acc0[v] + acc1[v] + acc2[v] + bias4[v];
        float gi = sat01(0.2f * p[0] + 0.5f);
        float gf = sat01(0.2f * p[1] + 0.5f);
        float gg = clamp1(p[2]);
        float go = sat01(0.2f * p[3] + 0.5f);
        c_state = gf * c_state + gi * gg;
        float h1 = go * clamp1(c_state);

        // h1 (bf16) -> LDS for wave0's coalesced publish
        h1s[slot][col][wave * 4 + q] = f2bf(h1);

        // x(t+1) -> LDS slotn
        if (havex) {
            cvt_store(&xb[slotn][0][b0][k0], &xb[slotn][1][b0][k0], xr0);
            cvt_store(&xb[slotn][0][b1][k1], &xb[slotn][1][b1][k1], xr1);
            if (has2) cvt_store(&xb[slotn][0][b2][k2], &xb[slotn][1][b2][k2], xr2);
        }

        // out (cached path)
        out[(size_t)t * SSZ + (size_t)bOut * HDIM + jOut] = h1;

        __syncthreads();   // (A) h1s/xb ready

        // ---- wave0: coalesced publish h(t+1) + flag (R3's proven path) ----
        if (wave == 0) {
            const int b = lane >> 2, part = lane & 3;
            uint32x4 d = *(const uint32x4*)&h1s[slot][b][part * 8];
            unsigned short* dst = hb + (size_t)slotn * SSZ
                                + (size_t)(grp * GB + b) * HDIM + wgl * UPW + part * 8;
            asm volatile("global_store_dwordx4 %0, %1, off sc0 sc1\n\t"
                         "s_waitcnt vmcnt(0)" :: "v"(dst), "v"(d) : "memory");
            if (lane == 0)
                __hip_atomic_store(&fline[wgl], (uint32_t)(t + 2), __ATOMIC_RELAXED,
                                   __HIP_MEMORY_SCOPE_SYSTEM);
        }
    }
}

extern "C" void kernel_launch(void* const* d_in, const int* in_sizes, int n_in,
                              void* d_out, int out_size, void* d_ws, size_t ws_size,
                              hipStream_t stream) {
    const float* x   = (const float*)d_in[0];
    const float* wih = (const float*)d_in[1];
    const float* whh = (const float*)d_in[2];
    const float* bih = (const float*)d_in[3];
    const float* bhh = (const float*)d_in[4];
    float* out = (float*)d_out;

    unsigned short* hb = (unsigned short*)d_ws;                        // 2*SSZ ushorts
    uint32_t* flags = (uint32_t*)((char*)d_ws + (size_t)2 * SSZ * 2);  // 2 x 16 dwords

    hipMemsetAsync(flags, 0, 2 * 16 * sizeof(uint32_t), stream);

    void* args[] = {(void*)&x, (void*)&wih, (void*)&whh, (void*)&bih, (void*)&bhh,
                    (void*)&out, (void*)&hb, (void*)&flags};
    hipError_t e = hipLaunchCooperativeKernel((const void*)hard_lstm, dim3(NWG), dim3(NTH),
                                              args, 0, stream);
    if (e != hipSuccess) {
        hipLaunchKernelGGL(hard_lstm, dim3(NWG), dim3(NTH), 0, stream,
                           x, wih, whh, bih, bhh, out, hb, flags);
    }
}

// Round 12
// 9270.259 us; speedup vs baseline: 1.8430x; 1.8430x over previous
//
#include <hip/hip_runtime.h>
#include <stdint.h>

// HardLSTM R12 = R3 byte-for-byte (anchor reproduction run; only this comment
// block differs). Fence-free cross-wg protocol via L3-coherent (sc0 sc1) ops.
// 2 independent batch-groups x 10 wgs x 512thr; wave owns 16 gate-rows,
// full K=640 in registers (bf16 hi/lo). h state bf16-hi only, double-buffered
// in d_ws; per-wg flags (one 64B line per group). One __syncthreads per step.

#define T_STEPS 2000
#define BATCH   32
#define IDIM    320
#define HDIM    320
#define NWG     20
#define WPG     10
#define NTH     512
#define GB      16
#define UPW     32
#define LDK     328            // padded x-LDS stride (elems); 656B rows, 16B-aligned
#define HSLOT   (BATCH*HDIM)   // 10240 ushorts per h slot

typedef __attribute__((ext_vector_type(8))) short short8;
typedef __attribute__((ext_vector_type(4))) float f32x4;
typedef __attribute__((ext_vector_type(4))) unsigned short ushort4v;
typedef __attribute__((ext_vector_type(4))) unsigned int uint32x4;

static __device__ __forceinline__ unsigned short f2bf(float f) {
    uint32_t u = __float_as_uint(f);
    u += 0x7FFFu + ((u >> 16) & 1u);   // RTNE
    return (unsigned short)(u >> 16);
}
static __device__ __forceinline__ float bf2f(unsigned short s) {
    return __uint_as_float(((uint32_t)s) << 16);
}
static __device__ __forceinline__ float sat01(float v)  { return fminf(fmaxf(v, 0.f), 1.f); }
static __device__ __forceinline__ float clamp1(float v) { return fminf(fmaxf(v, -1.f), 1.f); }

static __device__ __forceinline__ void cvt_store(unsigned short* hi_p,
                                                 unsigned short* lo_p, float4 v) {
    ushort4v hi, lo;
    hi[0] = f2bf(v.x); lo[0] = f2bf(v.x - bf2f(hi[0]));
    hi[1] = f2bf(v.y); lo[1] = f2bf(v.y - bf2f(hi[1]));
    hi[2] = f2bf(v.z); lo[2] = f2bf(v.z - bf2f(hi[2]));
    hi[3] = f2bf(v.w); lo[3] = f2bf(v.w - bf2f(hi[3]));
    *(ushort4v*)hi_p = hi;
    *(ushort4v*)lo_p = lo;
}

__global__ __launch_bounds__(NTH, 2)
void hard_lstm(const float* __restrict__ x, const float* __restrict__ w_ih,
               const float* __restrict__ w_hh, const float* __restrict__ b_ih,
               const float* __restrict__ b_hh, float* __restrict__ out,
               unsigned short* __restrict__ hb, uint32_t* __restrict__ flags)
{
    __shared__ __align__(16) unsigned short xb[2][2][GB][LDK];  // [slot][hi/lo][b][k]
    __shared__ __align__(16) unsigned short h1s[2][GB][UPW];    // bf16 h1 scratch

    const int tid  = threadIdx.x;
    const int wgg  = blockIdx.x;
    const int grp  = wgg / WPG;
    const int wgl  = wgg % WPG;
    const int wave = tid >> 6;
    const int lane = tid & 63;
    const int col  = lane & 15;    // MFMA A-row / B-col (batch)
    const int q    = lane >> 4;    // k-chunk / output row-quad

    // ---- A fragments (weights) -> registers/AGPRs, bf16 hi/lo, K=640 ----
    short8 ahi[20], alo[20];
    {
        const int jA   = wgl * UPW + wave * 4 + (col >> 2);
        const int grow = (col & 3) * HDIM + jA;
        const float* wi = w_ih + (size_t)grow * IDIM;
        const float* wh = w_hh + (size_t)grow * HDIM;
        #pragma unroll
        for (int s = 0; s < 20; ++s) {
            #pragma unroll
            for (int jj = 0; jj < 8; ++jj) {
                int k = s * 32 + q * 8 + jj;
                float w = (k < IDIM) ? wi[k] : wh[k - IDIM];
                unsigned short hi = f2bf(w);
                ahi[s][jj] = (short)hi;
                alo[s][jj] = (short)f2bf(w - bf2f(hi));
            }
        }
    }

    const int jOut = wgl * UPW + wave * 4 + q;   // hidden unit owned by this lane
    const int bOut = grp * GB + col;             // batch owned by this lane
    float bias4[4];
    #pragma unroll
    for (int v = 0; v < 4; ++v)
        bias4[v] = b_ih[v * HDIM + jOut] + b_hh[v * HDIM + jOut];

    // staging indices (16 batches x 320 fp32 = 1280 float4)
    const int i0 = tid, i1 = tid + NTH, i2 = tid + 2 * NTH;
    const int sb0 = i0 / 80, sk0 = (i0 % 80) * 4;
    const int sb1 = i1 / 80, sk1 = (i1 % 80) * 4;
    const int sb2 = i2 / 80, sk2 = (i2 % 80) * 4;
    const bool has2 = (i2 < 1280);

    uint32_t* fline = flags + grp * 16;          // group's flag cacheline
    uint32_t* fpoll = &fline[lane % WPG];

    // h-fragment base (batch col, k-offset q*8), per slot
    const unsigned short* hp0 = hb + (size_t)bOut * HDIM + q * 8;

    // ---------- pre-loop (acts as step t=-1): h(0)=0, stage x(0), flag=1 ----------
    h1s[1][col][wave * 4 + q] = 0;
    {
        const float4* xs = (const float4*)(x + (size_t)(grp * GB) * IDIM);
        float4 v0 = xs[i0], v1 = xs[i1], v2 = {};
        if (has2) v2 = xs[i2];
        cvt_store(&xb[0][0][sb0][sk0], &xb[0][1][sb0][sk0], v0);
        cvt_store(&xb[0][0][sb1][sk1], &xb[0][1][sb1][sk1], v1);
        if (has2) cvt_store(&xb[0][0][sb2][sk2], &xb[0][1][sb2][sk2], v2);
    }
    __syncthreads();
    if (wave == 0) {
        const int b = lane >> 2, part = lane & 3;
        uint32x4 d = *(const uint32x4*)&h1s[1][b][part * 8];
        unsigned short* dst = hb + (size_t)(grp * GB + b) * HDIM + wgl * UPW + part * 8;
        asm volatile("global_store_dwordx4 %0, %1, off sc0 sc1\n\t"
                     "s_waitcnt vmcnt(0)" :: "v"(dst), "v"(d) : "memory");
        if (lane == 0)
            __hip_atomic_store(&fline[wgl], 1u, __ATOMIC_RELAXED, __HIP_MEMORY_SCOPE_SYSTEM);
    }

    float c_state = 0.f;

    #pragma unroll 1
    for (int t = 0; t < T_STEPS; ++t) {
        const int slot  = t & 1;
        const int slotn = slot ^ 1;

        // ---- x(t+1) prefetch (cached; consumed after gate math) ----
        float4 xr0 = {}, xr1 = {}, xr2 = {};
        const bool havex = (t + 1 < T_STEPS);
        if (havex) {
            const float4* xs = (const float4*)(x + ((size_t)(t + 1) * BATCH + grp * GB) * IDIM);
            xr0 = xs[i0]; xr1 = xs[i1];
            if (has2) xr2 = xs[i2];
        }

        // ---- poll: all 10 producer flags of this group >= t+1 (wave0) ----
        if (wave == 0) {
            const uint32_t tgt = (uint32_t)(t + 1);
            while (true) {
                uint32_t v = __hip_atomic_load(fpoll, __ATOMIC_RELAXED,
                                               __HIP_MEMORY_SCOPE_AGENT);
                if (__all((int)(v >= tgt))) break;
            }
        }
        __syncthreads();   // (B) flags seen

        // ---- h(t) B-fragments: 10x dwordx4, L3-coherent, single asm block ----
        uint32x4 hv[10];
        {
            const unsigned short* hp = hp0 + (size_t)slot * HSLOT;
            asm volatile(
                "global_load_dwordx4 %0, %10, off sc0 sc1\n\t"
                "global_load_dwordx4 %1, %10, off offset:64 sc0 sc1\n\t"
                "global_load_dwordx4 %2, %10, off offset:128 sc0 sc1\n\t"
                "global_load_dwordx4 %3, %10, off offset:192 sc0 sc1\n\t"
                "global_load_dwordx4 %4, %10, off offset:256 sc0 sc1\n\t"
                "global_load_dwordx4 %5, %10, off offset:320 sc0 sc1\n\t"
                "global_load_dwordx4 %6, %10, off offset:384 sc0 sc1\n\t"
                "global_load_dwordx4 %7, %10, off offset:448 sc0 sc1\n\t"
                "global_load_dwordx4 %8, %10, off offset:512 sc0 sc1\n\t"
                "global_load_dwordx4 %9, %10, off offset:576 sc0 sc1\n\t"
                "s_waitcnt vmcnt(0)"
                : "=&v"(hv[0]), "=&v"(hv[1]), "=&v"(hv[2]), "=&v"(hv[3]), "=&v"(hv[4]),
                  "=&v"(hv[5]), "=&v"(hv[6]), "=&v"(hv[7]), "=&v"(hv[8]), "=&v"(hv[9])
                : "v"(hp) : "memory");
        }

        // ---- MFMA: x-half 3-term (s=0..9), h-half 2-term (s=10..19) ----
        f32x4 acc0 = {0.f, 0.f, 0.f, 0.f};
        f32x4 acc1 = {0.f, 0.f, 0.f, 0.f};
        f32x4 acc2 = {0.f, 0.f, 0.f, 0.f};
        {
            const unsigned short* bxh = &xb[slot][0][col][q * 8];
            const unsigned short* bxl = &xb[slot][1][col][q * 8];
            #pragma unroll
            for (int s = 0; s < 10; ++s) {
                short8 bh = *(const short8*)(bxh + s * 32);
                short8 bl = *(const short8*)(bxl + s * 32);
                acc0 = __builtin_amdgcn_mfma_f32_16x16x32_bf16(ahi[s], bh, acc0, 0, 0, 0);
                acc1 = __builtin_amdgcn_mfma_f32_16x16x32_bf16(alo[s], bh, acc1, 0, 0, 0);
                acc2 = __builtin_amdgcn_mfma_f32_16x16x32_bf16(ahi[s], bl, acc2, 0, 0, 0);
            }
            #pragma unroll
            for (int s = 0; s < 10; ++s) {
                short8 bh = *(const short8*)&hv[s];
                acc0 = __builtin_amdgcn_mfma_f32_16x16x32_bf16(ahi[10 + s], bh, acc0, 0, 0, 0);
                acc1 = __builtin_amdgcn_mfma_f32_16x16x32_bf16(alo[10 + s], bh, acc1, 0, 0, 0);
            }
        }

        // ---- gate math: lane owns (batch bOut, unit jOut), gates v=0..3 ----
        float p[4];
        #pragma unroll
        for (int v = 0; v < 4; ++v) p[v] = acc0[v] + acc1[v] + acc2[v] + bias4[v];
        float gi = sat01(0.2f * p[0] + 0.5f);
        float gf = sat01(0.2f * p[1] + 0.5f);
        float gg = clamp1(p[2]);
        float go = sat01(0.2f * p[3] + 0.5f);
        c_state = gf * c_state + gi * gg;
        float h1 = go * clamp1(c_state);

        // h1 (bf16) -> LDS for wave0's coalesced publish
        h1s[slot][col][wave * 4 + q] = f2bf(h1);

        // x(t+1) -> LDS slotn
        if (havex) {
            cvt_store(&xb[slotn][0][sb0][sk0], &xb[slotn][1][sb0][sk0], xr0);
            cvt_store(&xb[slotn][0][sb1][sk1], &xb[slotn][1][sb1][sk1], xr1);
            if (has2) cvt_store(&xb[slotn][0][sb2][sk2], &xb[slotn][1][sb2][sk2], xr2);
        }

        // out (cached, not consumed cross-wg)
        out[(size_t)t * (BATCH * HDIM) + (size_t)bOut * HDIM + jOut] = h1;

        __syncthreads();

        // ---- publish h(t+1) + flag (wave0 only; wave-internal ordering) ----
        if (wave == 0) {
            const int b = lane >> 2, part = lane & 3;
            uint32x4 d = *(const uint32x4*)&h1s[slot][b][part * 8];
            unsigned short* dst = hb + (size_t)slotn * HSLOT
                                + (size_t)(grp * GB + b) * HDIM + wgl * UPW + part * 8;
            asm volatile("global_store_dwordx4 %0, %1, off sc0 sc1\n\t"
                         "s_waitcnt vmcnt(0)" :: "v"(dst), "v"(d) : "memory");
            if (lane == 0)
                __hip_atomic_store(&fline[wgl], (uint32_t)(t + 2), __ATOMIC_RELAXED,
                                   __HIP_MEMORY_SCOPE_SYSTEM);
        }
    }
}

extern "C" void kernel_launch(void* const* d_in, const int* in_sizes, int n_in,
                              void* d_out, int out_size, void* d_ws, size_t ws_size,
                              hipStream_t stream) {
    const float* x   = (const float*)d_in[0];
    const float* wih = (const float*)d_in[1];
    const float* whh = (const float*)d_in[2];
    const float* bih = (const float*)d_in[3];
    const float* bhh = (const float*)d_in[4];
    float* out = (float*)d_out;

    unsigned short* hb = (unsigned short*)d_ws;                      // 2*HSLOT ushorts = 40960 B
    uint32_t* flags = (uint32_t*)((char*)d_ws + (size_t)2 * HSLOT * 2);

    hipMemsetAsync(flags, 0, 2 * 16 * sizeof(uint32_t), stream);

    void* args[] = {(void*)&x, (void*)&wih, (void*)&whh, (void*)&bih, (void*)&bhh,
                    (void*)&out, (void*)&hb, (void*)&flags};
    hipError_t e = hipLaunchCooperativeKernel((const void*)hard_lstm, dim3(NWG), dim3(NTH),
                                              args, 0, stream);
    if (e != hipSuccess) {
        hipLaunchKernelGGL(hard_lstm, dim3(NWG), dim3(NTH), 0, stream,
                           x, wih, whh, bih, bhh, out, hb, flags);
    }
}